// Round 5
// baseline (449.180 us; speedup 1.0000x reference)
//
#include <hip/hip_runtime.h>
#include <cstdint>
#include <cstddef>

// Problem constants
#define NB 4096
#define NL 50
#define NT 64
#define NF 3
#define NH 20
#define NO 16
#define NN (NB*NL)    // 204800 sequences
#define SB 16         // sequences per wave
#define WPB 2         // waves per block (fine-grained drain)
#define TS 16         // steps per x tile
#define HSTR 20       // hbf stride (shorts per seq) -> conflict-free pattern
#define XSTR 8        // xbf shorts per (k,seq): {xh0,xh1,xh2,bias, xl0,xl1,xl2, 0}
#define SCH (NN/64)   // 3200 sequences per sort chunk

typedef __attribute__((ext_vector_type(8))) short bf16x8;   // 8 bf16 = 4 VGPR
typedef __attribute__((ext_vector_type(4))) float f32x4;
typedef uint2 u2a __attribute__((may_alias));
typedef uint4 u4a __attribute__((may_alias));

// ---------------- fast transcendentals ----------------
#if defined(__has_builtin)
#  if __has_builtin(__builtin_amdgcn_exp2f)
#    define EXP2(x) __builtin_amdgcn_exp2f(x)
#  endif
#endif
#ifndef EXP2
extern "C" __device__ float __ocml_exp2_f32(float);
#  define EXP2(x) __ocml_exp2_f32(x)
#endif

__device__ __forceinline__ float fsig(float z) {
    return __builtin_amdgcn_rcpf(1.0f + __expf(-z));
}
__device__ __forceinline__ unsigned short f2bf(float f) {   // RNE fp32->bf16
    unsigned int x = __float_as_uint(f);
    x = (x + 0x7fffu + ((x >> 16) & 1u)) >> 16;
    return (unsigned short)x;
}
__device__ __forceinline__ float bf2f(unsigned short u) {
    return __uint_as_float(((unsigned int)u) << 16);
}
// packed RNE f32x2 -> bf16x2: D = [bf(a) | bf(b)<<16]
__device__ __forceinline__ unsigned int cvtpk(float a, float b) {
    unsigned int r;
    asm("v_cvt_pk_bf16_f32 %0, %1, %2" : "=v"(r) : "v"(a), "v"(b));
    return r;
}

// ---------------- W fragment precompute (device body) ----------------
// wfrag K rows: 0..19 w_hh, 20..22 w_ih (B=x_hi), 23 bias (b_ih+b_hh, B=1.0),
// 24..26 w_ih again (B=x_lo), 27..31 zero. Row m <-> gate g=(m&3)*20+T*4+(m>>2).
// log2e folded: gates i,f,o scaled by -log2(e); gate g scaled by +2*log2(e).
__device__ void wfrag_body(int l,
                           const float* __restrict__ w_hh,
                           const float* __restrict__ b_ih,
                           const float* __restrict__ b_hh,
                           const float* __restrict__ w_ih,
                           unsigned int* __restrict__ wfrag)
{
    int m = l & 15, kg = l >> 4;
    for (int T = 0; T < 5; ++T) {
        int g = (m & 3) * 20 + T * 4 + (m >> 2);
        int jt = g / 20;              // 0=i 1=f 2=g 3=o
        float sc = (jt == 2) ? 2.8853900817779268f : -1.4426950408889634f;
        unsigned int hi[4], lo[4];
        for (int d = 0; d < 4; ++d) {
            unsigned int hw[2], lw[2];
            for (int e = 0; e < 2; ++e) {
                int k = kg * 8 + d * 2 + e;
                float v = 0.0f;
                if (k < 20)       v = w_hh[g * 20 + k];
                else if (k <= 22) v = w_ih[g * 3 + (k - 20)];
                else if (k == 23) v = b_ih[g] + b_hh[g];
                else if (k <= 26) v = w_ih[g * 3 + (k - 24)];
                v *= sc;
                unsigned short h16 = f2bf(v);
                float r = v - bf2f(h16);
                hw[e] = h16; lw[e] = f2bf(r);
            }
            hi[d] = hw[0] | (hw[1] << 16);
            lo[d] = lw[0] | (lw[1] << 16);
        }
        for (int d = 0; d < 4; ++d) {
            wfrag[(size_t)((T * 2 + 0) * 64 + l) * 4 + d] = hi[d];
            wfrag[(size_t)((T * 2 + 1) * 64 + l) * 4 + d] = lo[d];
        }
    }
}

// ---------------- atomic-free counting sort + wfrag (65 blocks) ------------
// Blocks 0..63: per-chunk histogram via LDS, plain-stored to bhist[b][l].
// Block 64: W fragment precompute (independent work, fully overlapped).
__global__ __launch_bounds__(256) void hist64_kernel(
    const int* __restrict__ lengths, int* __restrict__ bhist,
    const float* __restrict__ w_hh, const float* __restrict__ b_ih,
    const float* __restrict__ b_hh, const float* __restrict__ w_ih,
    unsigned int* __restrict__ wfrag)
{
    const int b = blockIdx.x;
    const int tid = threadIdx.x;
    if (b == 64) {
        if (tid < 64) wfrag_body(tid, w_hh, b_ih, b_hh, w_ih, wfrag);
        return;
    }
    __shared__ int lh[64];
    if (tid < 64) lh[tid] = 0;
    __syncthreads();
    const int base = b * SCH;
    for (int i = tid; i < SCH; i += 256) {
        int len = lengths[base + i];
        len = len < 0 ? 0 : (len > 63 ? 63 : len);
        atomicAdd(&lh[len], 1);
    }
    __syncthreads();
    if (tid < 64) bhist[b * 64 + tid] = lh[tid];
}

// Single-pass scatter; each block derives its own bucket bases from bhist
// (64x64 ints, L2-hot) -- no separate prefix kernel, no global atomics.
__global__ __launch_bounds__(256) void scatter64_kernel(
    const int* __restrict__ lengths,
    const int* __restrict__ bhist,
    int* __restrict__ order,
    int* __restrict__ len_s)
{
    __shared__ int lcnt[64];
    __shared__ int lbase[64];
    const int tid = threadIdx.x;
    const int b   = blockIdx.x;
    if (tid < 64) {
        const int l = tid;
        int tot = 0, pre = 0;
#pragma unroll 16
        for (int bb = 0; bb < 64; ++bb) {
            int v = bhist[bb * 64 + l];
            tot += v;
            if (bb < b) pre += v;
        }
        int s = tot;                      // exclusive scan over l -> base[l]
#pragma unroll
        for (int d = 1; d < 64; d <<= 1) {
            int o = __shfl_up(s, d);
            if (l >= d) s += o;
        }
        lbase[l] = (s - tot) + pre;
        lcnt[l] = 0;
    }
    __syncthreads();
    const int base = b * SCH;
    for (int i = tid; i < SCH; i += 256) {
        int n = base + i;
        int len = lengths[n];
        len = len < 0 ? 0 : (len > 63 ? 63 : len);
        int r = atomicAdd(&lcnt[len], 1);
        int pos = lbase[len] + r;
        order[pos] = n;
        len_s[pos] = len;
    }
}

// ---------------- LSTM + summary linear (MFMA, 2 independent waves/block) ----
// Gate math: 2^x form, scales folded into weights.  Per STEP (5 units):
// 25 exp + 2 rcp -- the 10 per-unit rcps are replaced by two Montgomery
// batch-inversions (prefix/suffix products, 15 mul + 1 rcp per group of 5).
// Overflow-safe: dd <= ~1e7 each (data-bounded) -> prod5 < 1e36 < fp32 max;
// tanh-exp clamp lowered 43.3 -> 14.5 (tanh err <= 8.6e-5) so the second
// group's prod5 < 1e28.  Step loop split at wavemin (sorted groups nearly
// uniform); blocks launched longest-first.
#define LSTM_STEP(K, MASKED)                                                     \
    {                                                                            \
        uint2 ra_ = *(const u2a*)(p1 + (K) * st1);                               \
        uint2 rb_ = *(const u2a*)(p2 + (K) * st2);                               \
        union { uint4 u; bf16x8 v; } bb_;                                        \
        bb_.u = make_uint4(ra_.x, ra_.y, rb_.x, rb_.y);                          \
        f32x4 acc[5];                                                            \
        _Pragma("unroll")                                                        \
        for (int T = 0; T < 5; ++T) {                                            \
            f32x4 z4 = {0.f, 0.f, 0.f, 0.f};                                     \
            z4     = __builtin_amdgcn_mfma_f32_16x16x32_bf16(wf[2*T],   bb_.v, z4, 0, 0, 0); \
            acc[T] = __builtin_amdgcn_mfma_f32_16x16x32_bf16(wf[2*T+1], bb_.v, z4, 0, 0, 0); \
        }                                                                        \
        bool m_ = true;                                                          \
        if (MASKED) m_ = (t0 + (K)) < mylen;                                     \
        float num_[5], dd_[5], ao_[5];                                           \
        _Pragma("unroll")                                                        \
        for (int T = 0; T < 5; ++T) {                                            \
            float Ei = EXP2(acc[T][0]);          /* exp(-zi) */                  \
            float Ef = EXP2(acc[T][1]);          /* exp(-zf) */                  \
            float G  = EXP2(acc[T][2]);          /* exp(2*zg) */                 \
            float Ai = 1.0f + Ei, Af = 1.0f + Ef, Bg = 1.0f + G;                 \
            float t1 = Ai * Bg;                                                  \
            num_[T] = fmaf(G - 1.0f, Af, c5[T] * t1);                            \
            dd_[T]  = t1 * Af;                                                   \
            ao_[T]  = acc[T][3];                                                 \
        }                                                                        \
        float s0_ = dd_[0], s1_ = s0_ * dd_[1], s2_ = s1_ * dd_[2];              \
        float s3_ = s2_ * dd_[3], P_ = s3_ * dd_[4];                             \
        float u3_ = dd_[3] * dd_[4], u2_ = dd_[2] * u3_, u1_ = dd_[1] * u2_;     \
        float R_ = __builtin_amdgcn_rcpf(P_);                                    \
        float cn_[5];                                                            \
        cn_[0] = num_[0] * (R_ * u1_);                                           \
        cn_[1] = num_[1] * (R_ * s0_ * u2_);                                     \
        cn_[2] = num_[2] * (R_ * s1_ * u3_);                                     \
        cn_[3] = num_[3] * (R_ * s2_ * dd_[4]);                                  \
        cn_[4] = num_[4] * (R_ * s3_);                                           \
        float em_[5], e2_[5];                                                    \
        _Pragma("unroll")                                                        \
        for (int T = 0; T < 5; ++T) {                                            \
            float ce2 = fminf(cn_[T] * 2.8853900817779268f, 14.5f);              \
            float Ec  = EXP2(ce2);               /* exp(2*clamp(cn)) */          \
            float Eo  = EXP2(ao_[T]);            /* exp(-zo) */                  \
            em_[T] = Ec - 1.0f;                                                  \
            e2_[T] = (1.0f + Eo) * (1.0f + Ec);                                  \
        }                                                                        \
        float q0_ = e2_[0], q1_ = q0_ * e2_[1], q2_ = q1_ * e2_[2];              \
        float q3_ = q2_ * e2_[3], Q_ = q3_ * e2_[4];                             \
        float v3_ = e2_[3] * e2_[4], v2_ = e2_[2] * v3_, v1_ = e2_[1] * v2_;     \
        float R2_ = __builtin_amdgcn_rcpf(Q_);                                   \
        float hn_[5];                                                            \
        hn_[0] = em_[0] * (R2_ * v1_);                                           \
        hn_[1] = em_[1] * (R2_ * q0_ * v2_);                                     \
        hn_[2] = em_[2] * (R2_ * q1_ * v3_);                                     \
        hn_[3] = em_[3] * (R2_ * q2_ * e2_[4]);                                  \
        hn_[4] = em_[4] * (R2_ * q3_);                                           \
        _Pragma("unroll")                                                        \
        for (int T = 0; T < 5; ++T) {                                            \
            unsigned int hp_ = cvtpk(hn_[T], hn_[T]);                            \
            if (m_) {                                                            \
                c5[T] = cn_[T];                                                  \
                hbf[wid][hoff + T * 4] = (unsigned short)hp_;                    \
            }                                                                    \
        }                                                                        \
    }

__global__ __launch_bounds__(128) void lstm_kernel(
    const float* __restrict__ x,        // [NN][64][3]
    const int*   __restrict__ len_s,    // [NN] sorted lengths
    const int*   __restrict__ order,    // [NN] sorted indices
    const unsigned int* __restrict__ wfrag, // [10][64][4]
    const float* __restrict__ w_lin,    // [16][20]
    const float* __restrict__ b_lin,    // [16]
    float* __restrict__ feat)           // [NN][16]
{
    __shared__ __align__(16) unsigned short hbf[WPB][SB * HSTR];       // 1.25 KB
    __shared__ __align__(16) unsigned short xbf[WPB][TS * SB * XSTR];  // 8 KB
    __shared__ __align__(16) unsigned short zbuf[WPB][8];              // 32 B

    const int tid  = threadIdx.x;
    const int wid  = __builtin_amdgcn_readfirstlane(tid >> 6);
    const int lane = tid & 63;
    const int n16  = lane & 15;
    const int kg   = lane >> 4;
    // reverse order: longest-length segments launch first (tail balance)
    const int base = ((gridDim.x - 1 - blockIdx.x) * WPB + wid) * SB;

    const int mylen   = len_s[base + n16];
    const int wavemin = len_s[base];             // ascending sort
    const int wavemax = len_s[base + SB - 1];

    // per-wave LDS init (no cross-wave deps -> no barrier)
    for (int i = lane; i < SB * HSTR; i += 64) hbf[wid][i] = 0;
    if (lane < 8) zbuf[wid][lane] = 0;

    // W fragments: 5 tiles x {hi,lo}
    bf16x8 wf[10];
#pragma unroll
    for (int p = 0; p < 10; ++p) {
        union { uint4 i; bf16x8 v; } cv;
        cv.i = ((const uint4*)wfrag)[p * 64 + lane];
        wf[p] = cv.v;
    }

    // x gather map: lane = (seq ssl)<<2 | t-quarter tq; each lane owns 4
    // complete (t,seq) cells = 12 consecutive floats = 3 aligned float4.
    int nown = order[base + n16];
    const int ssl = lane >> 2;
    const int tq  = lane & 3;
    int nsl = __shfl(nown, ssl);
    const size_t gbase = (size_t)nsl * (NT * NF) + (size_t)tq * 12;  // floats

    // step-loop LDS addressing: frag = [p1: rows 8kg..8kg+3][p2: rows +4..+7]
    const unsigned short* hpw = &hbf[wid][n16 * HSTR];
    const unsigned short* p1 = (kg < 3) ? (hpw + kg * 8)
                                        : &xbf[wid][n16 * XSTR + 4];
    const unsigned short* p2 = (kg < 2) ? (hpw + kg * 8 + 4)
                             : (kg == 2 ? &xbf[wid][n16 * XSTR]
                                        : &zbuf[wid][0]);
    const int st1 = (kg == 3) ? SB * XSTR : 0;   // shorts per step
    const int st2 = (kg == 2) ? SB * XSTR : 0;
    const int hoff = n16 * HSTR + kg;

    float c5[5];
#pragma unroll
    for (int j = 0; j < 5; ++j) c5[j] = 0.0f;

    if (wavemax > 0) {
        float4 vf[3];
#pragma unroll
        for (int j = 0; j < 3; ++j) vf[j] = *(const float4*)(x + gbase + 4 * j);

        for (int t0 = 0; t0 < wavemax; t0 += TS) {
            // stage tile: 4 cells/lane, one ds_write_b128 per cell
            float f12[12] = {vf[0].x, vf[0].y, vf[0].z, vf[0].w,
                             vf[1].x, vf[1].y, vf[1].z, vf[1].w,
                             vf[2].x, vf[2].y, vf[2].z, vf[2].w};
#pragma unroll
            for (int jj = 0; jj < 4; ++jj) {
                float a0 = f12[3 * jj], a1 = f12[3 * jj + 1], a2 = f12[3 * jj + 2];
                unsigned int w0 = cvtpk(a0, a1);          // [xh0|xh1]
                unsigned int w1 = cvtpk(a2, 1.0f);        // [xh2|bias]
                float r0 = a0 - __uint_as_float(w0 << 16);
                float r1 = a1 - __uint_as_float(w0 & 0xFFFF0000u);
                float r2 = a2 - __uint_as_float(w1 << 16);
                unsigned int w2 = cvtpk(r0, r1);          // [xl0|xl1]
                unsigned int w3 = cvtpk(r2, 0.0f);        // [xl2|0]
                int t = tq * 4 + jj;
                *(u4a*)&xbf[wid][(t * SB + ssl) * XSTR] = make_uint4(w0, w1, w2, w3);
            }
            // prefetch next tile
            if (t0 + TS < wavemax) {
                size_t off = (size_t)(t0 + TS) * NF;
#pragma unroll
                for (int j = 0; j < 3; ++j)
                    vf[j] = *(const float4*)(x + gbase + off + 4 * j);
            }

            int kmax = wavemax - t0; if (kmax > TS) kmax = TS;
            int ku = wavemin - t0;
            ku = ku < 0 ? 0 : (ku > kmax ? kmax : ku);
            int k = 0;
            for (; k < ku; ++k)   LSTM_STEP(k, false)   // all lanes active
            for (; k < kmax; ++k) LSTM_STEP(k, true)    // masked tail
        }
    }

    // epilogue: summary linear. Lane (n16,kg) -> outputs o = 4*kg..4*kg+3
    float hl[NH];
#pragma unroll
    for (int u = 0; u < NH; ++u) hl[u] = bf2f(hbf[wid][n16 * HSTR + u]);
    float4 res;
    if (mylen > 0) {
        float r4[4];
#pragma unroll
        for (int j = 0; j < 4; ++j) {
            int o = 4 * kg + j;
            float aa = b_lin[o];
#pragma unroll
            for (int kk = 0; kk < NH; ++kk) aa += w_lin[o * NH + kk] * hl[kk];
            r4[j] = fsig(aa);
        }
        res = make_float4(r4[0], r4[1], r4[2], r4[3]);
    } else {
        res = make_float4(0.f, 0.f, 0.f, 0.f);
    }
    *(float4*)(feat + (size_t)nown * NO + 4 * kg) = res;
}

// ---------------- conv stack + fc head: 2 batch rows per block ----
// Wave q handles oc q*8..q*8+7 (wave-uniform weight indices -> s_load path).
// conv1 (46 pos) loops both batches (weights amortized 2x).  conv2/conv3
// (22/19 pos) put batch 0 on lanes 0..31 and batch 1 on lanes 32..63 ->
// per-batch VALU instruction count halves.  fc1/fc2 run on waves 0 and 1.
__global__ __launch_bounds__(256) void head_kernel(
    const float* __restrict__ feat,  // [NB][NL][16]
    const float* __restrict__ c1w, const float* __restrict__ c1b,
    const float* __restrict__ c2w, const float* __restrict__ c2b,
    const float* __restrict__ c3w, const float* __restrict__ c3b,
    const float* __restrict__ f1w, const float* __restrict__ f1b,
    const float* __restrict__ f2w, const float* __restrict__ f2b,
    float* __restrict__ out)         // [NB][4]
{
    const int b0  = blockIdx.x * 2;
    const int tid = threadIdx.x;
    const int p   = tid & 63;
    const int q   = __builtin_amdgcn_readfirstlane(tid >> 6);  // oc-octet 0..3
    const int half = p >> 5;         // batch within wave (conv2/3)
    const int pp   = p & 31;         // position within half

    __shared__ float sf[2][16 * 50];   // 6.4 KB
    __shared__ float y1[2][32 * 46];   // 11.8 KB
    __shared__ float y2[2][32 * 22];   // 5.6 KB
    __shared__ __align__(16) float y3[2][32 * 19];   // 4.9 KB (608 floats)
    __shared__ float r1[2][16];

    for (int i = tid; i < 2 * NL * NO; i += 256) {
        int bb = (i >= NL * NO) ? 1 : 0;
        int j = i - bb * (NL * NO);
        int l = j >> 4, o = j & 15;
        sf[bb][o * 50 + l] = feat[(size_t)(b0 + bb) * (NL * NO) + j];
    }
    __syncthreads();

    const int oc0 = q * 8;

    // conv1: 16ch k5 s1 -> 32ch x 46, relu. Two passes (one per batch);
    // weights are wave-uniform and hoisted across passes.
#pragma unroll
    for (int bb = 0; bb < 2; ++bb) {
        if (p < 46) {
            float acc[8];
#pragma unroll
            for (int oc = 0; oc < 8; ++oc) acc[oc] = c1b[oc0 + oc];
#pragma unroll
            for (int ic = 0; ic < 16; ++ic) {
#pragma unroll
                for (int tap = 0; tap < 5; ++tap) {
                    float fv = sf[bb][ic * 50 + p + tap];
#pragma unroll
                    for (int oc = 0; oc < 8; ++oc)
                        acc[oc] += c1w[((oc0 + oc) * 16 + ic) * 5 + tap] * fv;
                }
            }
#pragma unroll
            for (int oc = 0; oc < 8; ++oc)
                y1[bb][(oc0 + oc) * 46 + p] = fmaxf(acc[oc], 0.0f);
        }
    }
    __syncthreads();

    // conv2: 32ch k4 s2 -> 32ch x 22, relu. half = batch, pp = position.
    if (pp < 22) {
        float acc[8];
#pragma unroll
        for (int oc = 0; oc < 8; ++oc) acc[oc] = c2b[oc0 + oc];
#pragma unroll
        for (int ic = 0; ic < 32; ++ic) {
#pragma unroll
            for (int tap = 0; tap < 4; ++tap) {
                float fv = y1[half][ic * 46 + 2 * pp + tap];
#pragma unroll
                for (int oc = 0; oc < 8; ++oc)
                    acc[oc] += c2w[((oc0 + oc) * 32 + ic) * 4 + tap] * fv;
            }
        }
#pragma unroll
        for (int oc = 0; oc < 8; ++oc)
            y2[half][(oc0 + oc) * 22 + pp] = fmaxf(acc[oc], 0.0f);
    }
    __syncthreads();

    // conv3: 32ch k4 s1 -> 32ch x 19, relu
    if (pp < 19) {
        float acc[8];
#pragma unroll
        for (int oc = 0; oc < 8; ++oc) acc[oc] = c3b[oc0 + oc];
#pragma unroll
        for (int ic = 0; ic < 32; ++ic) {
#pragma unroll
            for (int tap = 0; tap < 4; ++tap) {
                float fv = y2[half][ic * 22 + pp + tap];
#pragma unroll
                for (int oc = 0; oc < 8; ++oc)
                    acc[oc] += c3w[((oc0 + oc) * 32 + ic) * 4 + tap] * fv;
            }
        }
#pragma unroll
        for (int oc = 0; oc < 8; ++oc)
            y3[half][(oc0 + oc) * 19 + pp] = fmaxf(acc[oc], 0.0f);
    }
    __syncthreads();

    // fc1: 608 -> 16, relu. Wave 0 -> batch 0, wave 1 -> batch 1.
    // float4 weight loads + same-address (broadcast) float4 LDS reads.
    if (q < 2) {
        int u  = p & 15;
        int qq = p >> 4;
        const float4* wv = (const float4*)(f1w + u * 608 + qq * 152);
        const float4* yv = (const float4*)(&y3[q][qq * 152]);
        float acc = 0.0f;
#pragma unroll 2
        for (int k = 0; k < 38; ++k) {
            float4 a = wv[k], bv = yv[k];
            acc += a.x * bv.x + a.y * bv.y + a.z * bv.z + a.w * bv.w;
        }
        acc += __shfl_xor(acc, 16);
        acc += __shfl_xor(acc, 32);
        if (p < 16) r1[q][p] = fmaxf(acc + f1b[p], 0.0f);
    }
    __syncthreads();

    // fc2: 16 -> 4. Wave 0 -> batch 0, wave 1 -> batch 1.
    if (q < 2 && p < 4) {
        float s = f2b[p];
#pragma unroll
        for (int k = 0; k < 16; ++k) s += f2w[p * 16 + k] * r1[q][k];
        out[(size_t)(b0 + q) * 4 + p] = s;
    }
}

extern "C" void kernel_launch(void* const* d_in, const int* in_sizes, int n_in,
                              void* d_out, int out_size, void* d_ws, size_t ws_size,
                              hipStream_t stream)
{
    const float* x     = (const float*)d_in[0];
    const int*  lengths= (const int*)  d_in[1];
    const float* w_ih  = (const float*)d_in[2];
    const float* w_hh  = (const float*)d_in[3];
    const float* b_ih  = (const float*)d_in[4];
    const float* b_hh  = (const float*)d_in[5];
    const float* w_lin = (const float*)d_in[6];
    const float* b_lin = (const float*)d_in[7];
    const float* c1w   = (const float*)d_in[8];
    const float* c1b   = (const float*)d_in[9];
    const float* c2w   = (const float*)d_in[10];
    const float* c2b   = (const float*)d_in[11];
    const float* c3w   = (const float*)d_in[12];
    const float* c3b   = (const float*)d_in[13];
    const float* f1w   = (const float*)d_in[14];
    const float* f1b   = (const float*)d_in[15];
    const float* f2w   = (const float*)d_in[16];
    const float* f2b   = (const float*)d_in[17];
    float* out = (float*)d_out;

    // workspace layout (~14.8 MB), all segments 16B-aligned
    char* ws      = (char*)d_ws;
    float* feat   = (float*)ws;                       // NN*16 floats
    int*   order  = (int*)(feat + (size_t)NN * NO);   // NN
    int*   len_s  = order + NN;                       // NN
    int*   bhist  = len_s + NN;                       // 64*64
    unsigned int* wfrag = (unsigned int*)(bhist + 64 * 64); // 2560

    hist64_kernel   <<<65, 256, 0, stream>>>(lengths, bhist,
                                             w_hh, b_ih, b_hh, w_ih, wfrag);
    scatter64_kernel<<<64, 256, 0, stream>>>(lengths, bhist, order, len_s);
    lstm_kernel     <<<NN / (SB * WPB), 128, 0, stream>>>(x, len_s, order, wfrag,
                                                          w_lin, b_lin, feat);
    head_kernel     <<<NB / 2, 256, 0, stream>>>(feat, c1w, c1b, c2w, c2b, c3w, c3b,
                                                 f1w, f1b, f2w, f2b, out);
}

// Round 6
// 431.403 us; speedup vs baseline: 1.0412x; 1.0412x over previous
//
#include <hip/hip_runtime.h>
#include <cstdint>
#include <cstddef>

// Problem constants
#define NB 4096
#define NL 50
#define NT 64
#define NF 3
#define NH 20
#define NO 16
#define NN (NB*NL)    // 204800 sequences
#define SB 16         // sequences per wave
#define WPB 2         // waves per block (fine-grained drain)
#define TS 16         // steps per x tile
#define HSTR 20       // hbf stride (shorts per seq) -> conflict-free pattern
#define XSTR 8        // xbf shorts per (k,seq): {xh0,xh1,xh2,bias, xl0,xl1,xl2, 0}
#define SCH (NN/64)   // 3200 sequences per sort chunk
#define FLAGV(b) (0x9E3779B9u + (unsigned)(b) * 0x85EBCA6Bu)

typedef __attribute__((ext_vector_type(8))) short bf16x8;   // 8 bf16 = 4 VGPR
typedef __attribute__((ext_vector_type(4))) float f32x4;
typedef uint2 u2a __attribute__((may_alias));
typedef uint4 u4a __attribute__((may_alias));

// ---------------- fast transcendentals ----------------
#if defined(__has_builtin)
#  if __has_builtin(__builtin_amdgcn_exp2f)
#    define EXP2(x) __builtin_amdgcn_exp2f(x)
#  endif
#endif
#ifndef EXP2
extern "C" __device__ float __ocml_exp2_f32(float);
#  define EXP2(x) __ocml_exp2_f32(x)
#endif

__device__ __forceinline__ float fsig(float z) {
    return __builtin_amdgcn_rcpf(1.0f + __expf(-z));
}
__device__ __forceinline__ unsigned short f2bf(float f) {   // RNE fp32->bf16
    unsigned int x = __float_as_uint(f);
    x = (x + 0x7fffu + ((x >> 16) & 1u)) >> 16;
    return (unsigned short)x;
}
__device__ __forceinline__ float bf2f(unsigned short u) {
    return __uint_as_float(((unsigned int)u) << 16);
}
// packed RNE f32x2 -> bf16x2: D = [bf(a) | bf(b)<<16]
__device__ __forceinline__ unsigned int cvtpk(float a, float b) {
    unsigned int r;
    asm("v_cvt_pk_bf16_f32 %0, %1, %2" : "=v"(r) : "v"(a), "v"(b));
    return r;
}

// ---------------- W fragment precompute (device body) ----------------
// wfrag K rows: 0..19 w_hh, 20..22 w_ih (B=x_hi), 23 bias (b_ih+b_hh, B=1.0),
// 24..26 w_ih again (B=x_lo), 27..31 zero. Row m <-> gate g=(m&3)*20+T*4+(m>>2).
// log2e folded: gates i,f,o scaled by -log2(e); gate g scaled by +2*log2(e).
__device__ void wfrag_body(int l,
                           const float* __restrict__ w_hh,
                           const float* __restrict__ b_ih,
                           const float* __restrict__ b_hh,
                           const float* __restrict__ w_ih,
                           unsigned int* __restrict__ wfrag)
{
    int m = l & 15, kg = l >> 4;
    for (int T = 0; T < 5; ++T) {
        int g = (m & 3) * 20 + T * 4 + (m >> 2);
        int jt = g / 20;              // 0=i 1=f 2=g 3=o
        float sc = (jt == 2) ? 2.8853900817779268f : -1.4426950408889634f;
        unsigned int hi[4], lo[4];
        for (int d = 0; d < 4; ++d) {
            unsigned int hw[2], lw[2];
            for (int e = 0; e < 2; ++e) {
                int k = kg * 8 + d * 2 + e;
                float v = 0.0f;
                if (k < 20)       v = w_hh[g * 20 + k];
                else if (k <= 22) v = w_ih[g * 3 + (k - 20)];
                else if (k == 23) v = b_ih[g] + b_hh[g];
                else if (k <= 26) v = w_ih[g * 3 + (k - 24)];
                v *= sc;
                unsigned short h16 = f2bf(v);
                float r = v - bf2f(h16);
                hw[e] = h16; lw[e] = f2bf(r);
            }
            hi[d] = hw[0] | (hw[1] << 16);
            lo[d] = lw[0] | (lw[1] << 16);
        }
        for (int d = 0; d < 4; ++d) {
            wfrag[(size_t)((T * 2 + 0) * 64 + l) * 4 + d] = hi[d];
            wfrag[(size_t)((T * 2 + 1) * 64 + l) * 4 + d] = lo[d];
        }
    }
}

// ---------------- merged sort + wfrag (single launch, 65 blocks) -----------
// Blocks 0..63: per-chunk LDS histogram -> bhist row -> release flag ->
// spin until all 64 flags set (all blocks co-resident: 65 << 256 CUs, so the
// barrier cannot deadlock) -> derive bucket bases -> single-pass scatter.
// Block 64: W fragment precompute (independent, overlapped).
// Flags are cleared by head_kernel each iteration (head provably runs after
// this kernel in stream order); flag values are non-trivial constants so
// leftover workspace poison cannot spuriously satisfy the wait.
__global__ __launch_bounds__(256) void sort_kernel(
    const int* __restrict__ lengths,
    int* __restrict__ bhist,
    unsigned int* __restrict__ flags,
    int* __restrict__ order,
    int* __restrict__ len_s,
    const float* __restrict__ w_hh, const float* __restrict__ b_ih,
    const float* __restrict__ b_hh, const float* __restrict__ w_ih,
    unsigned int* __restrict__ wfrag)
{
    const int b   = blockIdx.x;
    const int tid = threadIdx.x;
    if (b == 64) {
        if (tid < 64) wfrag_body(tid, w_hh, b_ih, b_hh, w_ih, wfrag);
        return;
    }
    __shared__ int lh[64];
    __shared__ int lcnt[64];
    __shared__ int lbase[64];
    if (tid < 64) lh[tid] = 0;
    __syncthreads();
    const int base = b * SCH;
    for (int i = tid; i < SCH; i += 256) {
        int len = lengths[base + i];
        len = len < 0 ? 0 : (len > 63 ? 63 : len);
        atomicAdd(&lh[len], 1);
    }
    __syncthreads();
    if (tid < 64) bhist[b * 64 + tid] = lh[tid];
    __syncthreads();
    if (tid == 0) {
        __threadfence();   // make bhist row visible at device scope
        __hip_atomic_store(&flags[b], FLAGV(b), __ATOMIC_RELEASE,
                           __HIP_MEMORY_SCOPE_AGENT);
    }
    if (tid < 64) {
        while (__hip_atomic_load(&flags[tid], __ATOMIC_ACQUIRE,
                                 __HIP_MEMORY_SCOPE_AGENT) != FLAGV(tid)) {
            __builtin_amdgcn_s_sleep(8);
        }
    }
    __syncthreads();
    __threadfence();       // acquire: invalidate local caches before bhist reads

    if (tid < 64) {
        const int l = tid;
        int tot = 0, pre = 0;
#pragma unroll 16
        for (int bb = 0; bb < 64; ++bb) {
            int v = bhist[bb * 64 + l];
            tot += v;
            if (bb < b) pre += v;
        }
        int s = tot;                      // exclusive scan over l -> base[l]
#pragma unroll
        for (int d = 1; d < 64; d <<= 1) {
            int o = __shfl_up(s, d);
            if (l >= d) s += o;
        }
        lbase[l] = (s - tot) + pre;
        lcnt[l] = 0;
    }
    __syncthreads();
    for (int i = tid; i < SCH; i += 256) {
        int n = base + i;
        int len = lengths[n];
        len = len < 0 ? 0 : (len > 63 ? 63 : len);
        int r = atomicAdd(&lcnt[len], 1);
        int pos = lbase[len] + r;
        order[pos] = n;
        len_s[pos] = len;
    }
}

// ---------------- LSTM + summary linear (MFMA, 2 independent waves/block) ----
// Gate math: 2^x form (scales folded into weights): 5 exp + 2 rcp per
// unit-step, independent chains across the 5 units (ILP).  [R5's Montgomery
// batch inversion reverted: rcp is a single ~8cy trans op; trading 8 rcp for
// ~30 serially-dependent muls lengthened the critical path, +12%.]
// h stored via single v_cvt_pk_bf16_f32 (RNE, same bits as f2bf).
// Step loop split at wavemin; blocks launched longest-first.
#define LSTM_STEP(K, MASKED)                                                     \
    {                                                                            \
        uint2 ra_ = *(const u2a*)(p1 + (K) * st1);                               \
        uint2 rb_ = *(const u2a*)(p2 + (K) * st2);                               \
        union { uint4 u; bf16x8 v; } bb_;                                        \
        bb_.u = make_uint4(ra_.x, ra_.y, rb_.x, rb_.y);                          \
        f32x4 acc[5];                                                            \
        _Pragma("unroll")                                                        \
        for (int T = 0; T < 5; ++T) {                                            \
            f32x4 z4 = {0.f, 0.f, 0.f, 0.f};                                     \
            z4     = __builtin_amdgcn_mfma_f32_16x16x32_bf16(wf[2*T],   bb_.v, z4, 0, 0, 0); \
            acc[T] = __builtin_amdgcn_mfma_f32_16x16x32_bf16(wf[2*T+1], bb_.v, z4, 0, 0, 0); \
        }                                                                        \
        bool m_ = true;                                                          \
        if (MASKED) m_ = (t0 + (K)) < mylen;                                     \
        _Pragma("unroll")                                                        \
        for (int T = 0; T < 5; ++T) {                                            \
            float Ei = EXP2(acc[T][0]);          /* exp(-zi) */                  \
            float Ef = EXP2(acc[T][1]);          /* exp(-zf) */                  \
            float G  = EXP2(acc[T][2]);          /* exp(2*zg) */                 \
            float Eo = EXP2(acc[T][3]);          /* exp(-zo) */                  \
            float Ai = 1.0f + Ei, Af = 1.0f + Ef, Bg = 1.0f + G;                 \
            float t1 = Ai * Bg;                                                  \
            float num = fmaf(G - 1.0f, Af, c5[T] * t1);                          \
            float cn  = num * __builtin_amdgcn_rcpf(t1 * Af);                    \
            float ce2 = fminf(cn * 2.8853900817779268f, 43.3f);                  \
            float Ec  = EXP2(ce2);               /* exp(2*clamp(cn)) */          \
            float hn  = (Ec - 1.0f) *                                            \
                        __builtin_amdgcn_rcpf((1.0f + Eo) * (1.0f + Ec));        \
        unsigned int hp_ = cvtpk(hn, hn);                                        \
        if (m_) {                                                                \
            c5[T] = cn;                                                          \
            hbf[wid][hoff + T * 4] = (unsigned short)hp_;                        \
        }                                                                        \
        }                                                                        \
    }

__global__ __launch_bounds__(128) void lstm_kernel(
    const float* __restrict__ x,        // [NN][64][3]
    const int*   __restrict__ len_s,    // [NN] sorted lengths
    const int*   __restrict__ order,    // [NN] sorted indices
    const unsigned int* __restrict__ wfrag, // [10][64][4]
    const float* __restrict__ w_lin,    // [16][20]
    const float* __restrict__ b_lin,    // [16]
    float* __restrict__ feat)           // [NN][16]
{
    __shared__ __align__(16) unsigned short hbf[WPB][SB * HSTR];       // 1.25 KB
    __shared__ __align__(16) unsigned short xbf[WPB][TS * SB * XSTR];  // 8 KB
    __shared__ __align__(16) unsigned short zbuf[WPB][8];              // 32 B

    const int tid  = threadIdx.x;
    const int wid  = __builtin_amdgcn_readfirstlane(tid >> 6);
    const int lane = tid & 63;
    const int n16  = lane & 15;
    const int kg   = lane >> 4;
    // reverse order: longest-length segments launch first (tail balance)
    const int base = ((gridDim.x - 1 - blockIdx.x) * WPB + wid) * SB;

    const int mylen   = len_s[base + n16];
    const int wavemin = len_s[base];             // ascending sort
    const int wavemax = len_s[base + SB - 1];

    // per-wave LDS init (no cross-wave deps -> no barrier)
    for (int i = lane; i < SB * HSTR; i += 64) hbf[wid][i] = 0;
    if (lane < 8) zbuf[wid][lane] = 0;

    // x gather map: lane = (seq ssl)<<2 | t-quarter tq; each lane owns 4
    // complete (t,seq) cells = 12 consecutive floats = 3 aligned float4.
    int nown = order[base + n16];
    const int ssl = lane >> 2;
    const int tq  = lane & 3;
    int nsl = __shfl(nown, ssl);
    const size_t gbase = (size_t)nsl * (NT * NF) + (size_t)tq * 12;  // floats

    // step-loop LDS addressing: frag = [p1: rows 8kg..8kg+3][p2: rows +4..+7]
    const unsigned short* hpw = &hbf[wid][n16 * HSTR];
    const unsigned short* p1 = (kg < 3) ? (hpw + kg * 8)
                                        : &xbf[wid][n16 * XSTR + 4];
    const unsigned short* p2 = (kg < 2) ? (hpw + kg * 8 + 4)
                             : (kg == 2 ? &xbf[wid][n16 * XSTR]
                                        : &zbuf[wid][0]);
    const int st1 = (kg == 3) ? SB * XSTR : 0;   // shorts per step
    const int st2 = (kg == 2) ? SB * XSTR : 0;
    const int hoff = n16 * HSTR + kg;

    float c5[5];
#pragma unroll
    for (int j = 0; j < 5; ++j) c5[j] = 0.0f;

    if (wavemax > 0) {
        // W fragments: 5 tiles x {hi,lo} (only needed when steps run)
        bf16x8 wf[10];
#pragma unroll
        for (int p = 0; p < 10; ++p) {
            union { uint4 i; bf16x8 v; } cv;
            cv.i = ((const uint4*)wfrag)[p * 64 + lane];
            wf[p] = cv.v;
        }

        float4 vf[3];
#pragma unroll
        for (int j = 0; j < 3; ++j) vf[j] = *(const float4*)(x + gbase + 4 * j);

        for (int t0 = 0; t0 < wavemax; t0 += TS) {
            // stage tile: 4 cells/lane, one ds_write_b128 per cell
            float f12[12] = {vf[0].x, vf[0].y, vf[0].z, vf[0].w,
                             vf[1].x, vf[1].y, vf[1].z, vf[1].w,
                             vf[2].x, vf[2].y, vf[2].z, vf[2].w};
#pragma unroll
            for (int jj = 0; jj < 4; ++jj) {
                float a0 = f12[3 * jj], a1 = f12[3 * jj + 1], a2 = f12[3 * jj + 2];
                unsigned int w0 = cvtpk(a0, a1);          // [xh0|xh1]
                unsigned int w1 = cvtpk(a2, 1.0f);        // [xh2|bias]
                float r0 = a0 - __uint_as_float(w0 << 16);
                float r1 = a1 - __uint_as_float(w0 & 0xFFFF0000u);
                float r2 = a2 - __uint_as_float(w1 << 16);
                unsigned int w2 = cvtpk(r0, r1);          // [xl0|xl1]
                unsigned int w3 = cvtpk(r2, 0.0f);        // [xl2|0]
                int t = tq * 4 + jj;
                *(u4a*)&xbf[wid][(t * SB + ssl) * XSTR] = make_uint4(w0, w1, w2, w3);
            }
            // prefetch next tile
            if (t0 + TS < wavemax) {
                size_t off = (size_t)(t0 + TS) * NF;
#pragma unroll
                for (int j = 0; j < 3; ++j)
                    vf[j] = *(const float4*)(x + gbase + off + 4 * j);
            }

            int kmax = wavemax - t0; if (kmax > TS) kmax = TS;
            int ku = wavemin - t0;
            ku = ku < 0 ? 0 : (ku > kmax ? kmax : ku);
            int k = 0;
            for (; k < ku; ++k)   LSTM_STEP(k, false)   // all lanes active
            for (; k < kmax; ++k) LSTM_STEP(k, true)    // masked tail
        }
    }

    // epilogue: summary linear. Lane (n16,kg) -> outputs o = 4*kg..4*kg+3
    float hl[NH];
#pragma unroll
    for (int u = 0; u < NH; ++u) hl[u] = bf2f(hbf[wid][n16 * HSTR + u]);
    float4 res;
    if (mylen > 0) {
        float r4[4];
#pragma unroll
        for (int j = 0; j < 4; ++j) {
            int o = 4 * kg + j;
            float aa = b_lin[o];
#pragma unroll
            for (int kk = 0; kk < NH; ++kk) aa += w_lin[o * NH + kk] * hl[kk];
            r4[j] = fsig(aa);
        }
        res = make_float4(r4[0], r4[1], r4[2], r4[3]);
    } else {
        res = make_float4(0.f, 0.f, 0.f, 0.f);
    }
    *(float4*)(feat + (size_t)nown * NO + 4 * kg) = res;
}

// ---------------- conv stack + fc head: 2 batch rows per block ----
// Wave q handles oc q*8..q*8+7 (wave-uniform weight indices -> s_load path).
// conv1 (46 pos) loops both batches (weights amortized 2x).  conv2/conv3
// (22/19 pos) put batch 0 on lanes 0..31 and batch 1 on lanes 32..63 ->
// per-batch VALU instruction count halves.  fc1/fc2 run on waves 0 and 1.
// Block 0 additionally clears the sort barrier flags for the next iteration.
__global__ __launch_bounds__(256) void head_kernel(
    const float* __restrict__ feat,  // [NB][NL][16]
    unsigned int* __restrict__ flags,
    const float* __restrict__ c1w, const float* __restrict__ c1b,
    const float* __restrict__ c2w, const float* __restrict__ c2b,
    const float* __restrict__ c3w, const float* __restrict__ c3b,
    const float* __restrict__ f1w, const float* __restrict__ f1b,
    const float* __restrict__ f2w, const float* __restrict__ f2b,
    float* __restrict__ out)         // [NB][4]
{
    const int b0  = blockIdx.x * 2;
    const int tid = threadIdx.x;
    const int p   = tid & 63;
    const int q   = __builtin_amdgcn_readfirstlane(tid >> 6);  // oc-octet 0..3
    const int half = p >> 5;         // batch within wave (conv2/3)
    const int pp   = p & 31;         // position within half

    if (blockIdx.x == 0 && tid < 64) flags[tid] = 0u;  // reset sort barrier

    __shared__ float sf[2][16 * 50];   // 6.4 KB
    __shared__ float y1[2][32 * 46];   // 11.8 KB
    __shared__ float y2[2][32 * 22];   // 5.6 KB
    __shared__ __align__(16) float y3[2][32 * 19];   // 4.9 KB (608 floats)
    __shared__ float r1[2][16];

    for (int i = tid; i < 2 * NL * NO; i += 256) {
        int bb = (i >= NL * NO) ? 1 : 0;
        int j = i - bb * (NL * NO);
        int l = j >> 4, o = j & 15;
        sf[bb][o * 50 + l] = feat[(size_t)(b0 + bb) * (NL * NO) + j];
    }
    __syncthreads();

    const int oc0 = q * 8;

    // conv1: 16ch k5 s1 -> 32ch x 46, relu. Two passes (one per batch);
    // weights are wave-uniform and hoisted across passes.
#pragma unroll
    for (int bb = 0; bb < 2; ++bb) {
        if (p < 46) {
            float acc[8];
#pragma unroll
            for (int oc = 0; oc < 8; ++oc) acc[oc] = c1b[oc0 + oc];
#pragma unroll
            for (int ic = 0; ic < 16; ++ic) {
#pragma unroll
                for (int tap = 0; tap < 5; ++tap) {
                    float fv = sf[bb][ic * 50 + p + tap];
#pragma unroll
                    for (int oc = 0; oc < 8; ++oc)
                        acc[oc] += c1w[((oc0 + oc) * 16 + ic) * 5 + tap] * fv;
                }
            }
#pragma unroll
            for (int oc = 0; oc < 8; ++oc)
                y1[bb][(oc0 + oc) * 46 + p] = fmaxf(acc[oc], 0.0f);
        }
    }
    __syncthreads();

    // conv2: 32ch k4 s2 -> 32ch x 22, relu. half = batch, pp = position.
    if (pp < 22) {
        float acc[8];
#pragma unroll
        for (int oc = 0; oc < 8; ++oc) acc[oc] = c2b[oc0 + oc];
#pragma unroll
        for (int ic = 0; ic < 32; ++ic) {
#pragma unroll
            for (int tap = 0; tap < 4; ++tap) {
                float fv = y1[half][ic * 46 + 2 * pp + tap];
#pragma unroll
                for (int oc = 0; oc < 8; ++oc)
                    acc[oc] += c2w[((oc0 + oc) * 32 + ic) * 4 + tap] * fv;
            }
        }
#pragma unroll
        for (int oc = 0; oc < 8; ++oc)
            y2[half][(oc0 + oc) * 22 + pp] = fmaxf(acc[oc], 0.0f);
    }
    __syncthreads();

    // conv3: 32ch k4 s1 -> 32ch x 19, relu
    if (pp < 19) {
        float acc[8];
#pragma unroll
        for (int oc = 0; oc < 8; ++oc) acc[oc] = c3b[oc0 + oc];
#pragma unroll
        for (int ic = 0; ic < 32; ++ic) {
#pragma unroll
            for (int tap = 0; tap < 4; ++tap) {
                float fv = y2[half][ic * 22 + pp + tap];
#pragma unroll
                for (int oc = 0; oc < 8; ++oc)
                    acc[oc] += c3w[((oc0 + oc) * 32 + ic) * 4 + tap] * fv;
            }
        }
#pragma unroll
        for (int oc = 0; oc < 8; ++oc)
            y3[half][(oc0 + oc) * 19 + pp] = fmaxf(acc[oc], 0.0f);
    }
    __syncthreads();

    // fc1: 608 -> 16, relu. Wave 0 -> batch 0, wave 1 -> batch 1.
    // float4 weight loads + same-address (broadcast) float4 LDS reads.
    if (q < 2) {
        int u  = p & 15;
        int qq = p >> 4;
        const float4* wv = (const float4*)(f1w + u * 608 + qq * 152);
        const float4* yv = (const float4*)(&y3[q][qq * 152]);
        float acc = 0.0f;
#pragma unroll 2
        for (int k = 0; k < 38; ++k) {
            float4 a = wv[k], bv = yv[k];
            acc += a.x * bv.x + a.y * bv.y + a.z * bv.z + a.w * bv.w;
        }
        acc += __shfl_xor(acc, 16);
        acc += __shfl_xor(acc, 32);
        if (p < 16) r1[q][p] = fmaxf(acc + f1b[p], 0.0f);
    }
    __syncthreads();

    // fc2: 16 -> 4. Wave 0 -> batch 0, wave 1 -> batch 1.
    if (q < 2 && p < 4) {
        float s = f2b[p];
#pragma unroll
        for (int k = 0; k < 16; ++k) s += f2w[p * 16 + k] * r1[q][k];
        out[(size_t)(b0 + q) * 4 + p] = s;
    }
}

extern "C" void kernel_launch(void* const* d_in, const int* in_sizes, int n_in,
                              void* d_out, int out_size, void* d_ws, size_t ws_size,
                              hipStream_t stream)
{
    const float* x     = (const float*)d_in[0];
    const int*  lengths= (const int*)  d_in[1];
    const float* w_ih  = (const float*)d_in[2];
    const float* w_hh  = (const float*)d_in[3];
    const float* b_ih  = (const float*)d_in[4];
    const float* b_hh  = (const float*)d_in[5];
    const float* w_lin = (const float*)d_in[6];
    const float* b_lin = (const float*)d_in[7];
    const float* c1w   = (const float*)d_in[8];
    const float* c1b   = (const float*)d_in[9];
    const float* c2w   = (const float*)d_in[10];
    const float* c2b   = (const float*)d_in[11];
    const float* c3w   = (const float*)d_in[12];
    const float* c3b   = (const float*)d_in[13];
    const float* f1w   = (const float*)d_in[14];
    const float* f1b   = (const float*)d_in[15];
    const float* f2w   = (const float*)d_in[16];
    const float* f2b   = (const float*)d_in[17];
    float* out = (float*)d_out;

    // workspace layout (~14.8 MB), all segments 16B-aligned
    char* ws      = (char*)d_ws;
    float* feat   = (float*)ws;                       // NN*16 floats
    int*   order  = (int*)(feat + (size_t)NN * NO);   // NN
    int*   len_s  = order + NN;                       // NN
    int*   bhist  = len_s + NN;                       // 64*64
    unsigned int* flags = (unsigned int*)(bhist + 64 * 64); // 64
    unsigned int* wfrag = flags + 64;                 // 2560

    sort_kernel <<<65, 256, 0, stream>>>(lengths, bhist, flags, order, len_s,
                                         w_hh, b_ih, b_hh, w_ih, wfrag);
    lstm_kernel <<<NN / (SB * WPB), 128, 0, stream>>>(x, len_s, order, wfrag,
                                                      w_lin, b_lin, feat);
    head_kernel <<<NB / 2, 256, 0, stream>>>(feat, flags,
                                             c1w, c1b, c2w, c2b, c3w, c3b,
                                             f1w, f1b, f2w, f2b, out);
}